// Round 3
// baseline (14888.544 us; speedup 1.0000x reference)
//
#include <hip/hip_runtime.h>
#include <hip/hip_bf16.h>

typedef __attribute__((ext_vector_type(8))) short short8;
typedef __attribute__((ext_vector_type(4))) float f32x4;

#define T_STEPS 512
#define BATCH   256
#define HDIM    1024
#define GDIM    4096   // 4*H

__device__ __forceinline__ float sigmoidf_(float x) {
  return 1.0f / (1.0f + __expf(-x));
}
__device__ __forceinline__ float tanh_(float x) {
  return 2.0f / (1.0f + __expf(-2.0f * x)) - 1.0f;
}
__device__ __forceinline__ short f2bf(float f) {
  __hip_bfloat16 h = __float2bfloat16(f);
  short s;
  __builtin_memcpy(&s, &h, sizeof(short));
  return s;
}

// ---------------------------------------------------------------------------
// Two-level grid barrier: 8 XCD-groups x 32 blocks. One block per CU, so
// thread-0 fences cover the whole block's L1 (per-CU) + L2 (per-XCD).
// ---------------------------------------------------------------------------
__device__ __forceinline__ void grid_barrier(unsigned* bar, int grp) {
  __syncthreads();                       // drains all block stores (vmcnt(0))
  if (threadIdx.x == 0) {
    __threadfence();                     // release: write back dirty L2
    unsigned* gcnt = bar + (size_t)grp * 32;   // 128B-separated counters
    unsigned* gctr = bar + 8 * 32;
    unsigned* gen  = bar + 8 * 32 + 32;
    unsigned g = __hip_atomic_load(gen, __ATOMIC_RELAXED, __HIP_MEMORY_SCOPE_AGENT);
    unsigned a = __hip_atomic_fetch_add(gcnt, 1u, __ATOMIC_ACQ_REL, __HIP_MEMORY_SCOPE_AGENT);
    if (a == 31u) {
      __hip_atomic_store(gcnt, 0u, __ATOMIC_RELAXED, __HIP_MEMORY_SCOPE_AGENT);
      unsigned ga = __hip_atomic_fetch_add(gctr, 1u, __ATOMIC_ACQ_REL, __HIP_MEMORY_SCOPE_AGENT);
      if (ga == 7u) {
        __hip_atomic_store(gctr, 0u, __ATOMIC_RELAXED, __HIP_MEMORY_SCOPE_AGENT);
        __hip_atomic_store(gen, g + 1u, __ATOMIC_RELEASE, __HIP_MEMORY_SCOPE_AGENT);
      } else {
        while (__hip_atomic_load(gen, __ATOMIC_RELAXED, __HIP_MEMORY_SCOPE_AGENT) == g)
          __builtin_amdgcn_s_sleep(1);
      }
    } else {
      while (__hip_atomic_load(gen, __ATOMIC_RELAXED, __HIP_MEMORY_SCOPE_AGENT) == g)
        __builtin_amdgcn_s_sleep(1);
    }
    __threadfence();                     // acquire: invalidate stale L1/L2
  }
  __syncthreads();
}

// ---------------------------------------------------------------------------
// Pack: Whb=bf16(Wh), Wxb=bf16(Wx) [4096][1024]; biasc = bx + bh
// ---------------------------------------------------------------------------
__global__ void pack_kernel(const float* __restrict__ Wh, const float* __restrict__ Wx,
                            const float* __restrict__ bx, const float* __restrict__ bh,
                            __hip_bfloat16* __restrict__ Whb,
                            __hip_bfloat16* __restrict__ Wxb,
                            float* __restrict__ biasc)
{
  const int stride = gridDim.x * blockDim.x;
  const int tid0 = blockIdx.x * blockDim.x + threadIdx.x;
  for (int i = tid0; i < GDIM * HDIM; i += stride) {
    Whb[i] = __float2bfloat16(Wh[i]);
    Wxb[i] = __float2bfloat16(Wx[i]);
  }
  for (int i = tid0; i < GDIM; i += stride)
    biasc[i] = bx[i] + bh[i];
}

// ---------------------------------------------------------------------------
// xg GEMM: xg[(t-t0)*256 + b][g] = bf16( x[b][t][:] . Wx[g][:] )
// 128x128 tile, 512 thr (8 waves 2x4), BK=64, dbuf LDS. B from bf16 Wxb.
// ---------------------------------------------------------------------------
__global__ __launch_bounds__(512, 1)
void xg_gemm(const float* __restrict__ x, const __hip_bfloat16* __restrict__ Wxb,
             __hip_bfloat16* __restrict__ xg, int t0)
{
  __shared__ short8 As[2][1024];
  __shared__ short8 Bs[2][1024];

  const int tid  = threadIdx.x;
  const int wave = tid >> 6;
  const int lane = tid & 63;

  const int cpx = gridDim.x >> 3;
  const int nb  = (blockIdx.x & 7) * cpx + (blockIdx.x >> 3);
  const int nt  = nb & 31;
  const int mt  = nb >> 5;

  const int trel  = mt >> 1;
  const int brow0 = (mt & 1) * 128;

  const int r0 = tid >> 3;   // 0..63
  const int cg = tid & 7;

  const float* asrc0 = x + ((size_t)(brow0 + r0) * T_STEPS + (t0 + trel)) * 1024 + cg * 8;
  const float* asrc1 = x + ((size_t)(brow0 + r0 + 64) * T_STEPS + (t0 + trel)) * 1024 + cg * 8;
  const __hip_bfloat16* bsrc0 = Wxb + (size_t)(nt * 128 + r0) * 1024 + cg * 8;
  const __hip_bfloat16* bsrc1 = Wxb + (size_t)(nt * 128 + r0 + 64) * 1024 + cg * 8;

  const int aslot0 = r0 * 8 + (cg ^ (r0 & 7));
  const int aslot1 = (r0 + 64) * 8 + (cg ^ (r0 & 7));

  f32x4 a0l, a0h, a1l, a1h;
  short8 bv0, bv1;

#define XG_LOAD(KC)                                        \
  do {                                                     \
    a0l = *(const f32x4*)(asrc0 + (KC) * 64);              \
    a0h = *(const f32x4*)(asrc0 + (KC) * 64 + 4);          \
    a1l = *(const f32x4*)(asrc1 + (KC) * 64);              \
    a1h = *(const f32x4*)(asrc1 + (KC) * 64 + 4);          \
    bv0 = *(const short8*)(const void*)(bsrc0 + (KC) * 64);\
    bv1 = *(const short8*)(const void*)(bsrc1 + (KC) * 64);\
  } while (0)

#define XG_WRITE(BUF)                                      \
  do {                                                     \
    short8 s0_, s1_;                                       \
    _Pragma("unroll")                                      \
    for (int e = 0; e < 4; ++e) {                          \
      s0_[e] = f2bf(a0l[e]); s0_[e + 4] = f2bf(a0h[e]);    \
      s1_[e] = f2bf(a1l[e]); s1_[e + 4] = f2bf(a1h[e]);    \
    }                                                      \
    As[BUF][aslot0] = s0_;                                 \
    As[BUF][aslot1] = s1_;                                 \
    Bs[BUF][aslot0] = bv0;                                 \
    Bs[BUF][aslot1] = bv1;                                 \
  } while (0)

  const int wr = wave >> 2;
  const int wc = wave & 3;

  f32x4 acc[4][2];
#pragma unroll
  for (int m = 0; m < 4; ++m)
#pragma unroll
    for (int n = 0; n < 2; ++n) acc[m][n] = (f32x4){0.f, 0.f, 0.f, 0.f};

  XG_LOAD(0);
  XG_WRITE(0);
  __syncthreads();

#pragma unroll 1
  for (int kc = 0; kc < 16; ++kc) {
    if (kc < 15) XG_LOAD(kc + 1);
    const int bs = kc & 1;
#pragma unroll
    for (int ks = 0; ks < 2; ++ks) {
      const int cgf = ks * 4 + (lane >> 4);
      short8 af[4], bfr[2];
#pragma unroll
      for (int m = 0; m < 4; ++m) {
        const int row = wr * 64 + m * 16 + (lane & 15);
        af[m] = As[bs][row * 8 + (cgf ^ (row & 7))];
      }
#pragma unroll
      for (int n = 0; n < 2; ++n) {
        const int row = wc * 32 + n * 16 + (lane & 15);
        bfr[n] = Bs[bs][row * 8 + (cgf ^ (row & 7))];
      }
#pragma unroll
      for (int m = 0; m < 4; ++m)
#pragma unroll
        for (int n = 0; n < 2; ++n)
          acc[m][n] = __builtin_amdgcn_mfma_f32_16x16x32_bf16(af[m], bfr[n], acc[m][n], 0, 0, 0);
    }
    if (kc < 15) XG_WRITE((kc + 1) & 1);
    __syncthreads();
  }

  const int dcol = lane & 15;
  const int dr0  = (lane >> 4) * 4;
#pragma unroll
  for (int m = 0; m < 4; ++m) {
#pragma unroll
    for (int n = 0; n < 2; ++n) {
      const int ocol = nt * 128 + wc * 32 + n * 16 + dcol;
#pragma unroll
      for (int rr = 0; rr < 4; ++rr) {
        const int orow = mt * 128 + wr * 64 + m * 16 + dr0 + rr;
        xg[(size_t)orow * GDIM + ocol] = __float2bfloat16(acc[m][n][rr]);
      }
    }
  }
#undef XG_LOAD
#undef XG_WRITE
}

// ---------------------------------------------------------------------------
// Persistent LSTM: W steps per launch, grid barrier between steps.
// 256 blocks (1/CU) x 512 thr. Block tile: 64 batch x (16 j-cols x 4 gates).
// Wh slice (64 rows x K=1024 bf16 = 128 KB) resident in LDS; c in registers.
// ---------------------------------------------------------------------------
__global__ __launch_bounds__(512, 1)
void lstm_persist(const __hip_bfloat16* __restrict__ xg,
                  const __hip_bfloat16* __restrict__ Whb,
                  const float* __restrict__ biasc,
                  const float* __restrict__ c2c,
                  __hip_bfloat16* __restrict__ hb0,
                  __hip_bfloat16* __restrict__ hb1,
                  float* __restrict__ c_st,
                  unsigned* __restrict__ bar,
                  int W)
{
  __shared__ short8 Bp[8192];      // 128 KB persistent Wh slice
  __shared__ short8 As[2][512];    // 16 KB dbuf: 64 rows x 8 granules (64k)

  const int tid  = threadIdx.x;
  const int wave = tid >> 6;
  const int lane = tid & 63;

  const int bid   = blockIdx.x;
  const int xcd   = bid & 7;
  const int idx   = bid >> 3;
  const int ntile = xcd * 8 + (idx & 7);   // 0..63
  const int mtile = idx >> 3;              // 0..3
  const int b0 = mtile * 64;
  const int j0 = ntile * 16;

  // ---- fill persistent B (Wh slice) ----
  for (int i = tid; i < 8192; i += 512) {
    const int row = i >> 7, ck = i & 127;
    const int grow = (row >> 4) * HDIM + j0 + (row & 15);   // gate*1024 + j
    Bp[row * 128 + (ck ^ (row & 7))] =
        *(const short8*)(const void*)(Whb + (size_t)grow * HDIM + ck * 8);
  }

  // ---- staging geometry ----
  const int r0  = tid >> 3;   // 0..63
  const int cg0 = tid & 7;
  const int aslot = r0 * 8 + (cg0 ^ (r0 & 7));
  const size_t hoff = (size_t)(b0 + r0) * HDIM + cg0 * 8;

  // ---- compute geometry ----
  const int rf = wave & 3;    // 16-row fragment
  const int kh = wave >> 2;   // k-half
  const int arow = rf * 16 + (lane & 15);
  const int colg = kh * 4 + (lane >> 4);
  const int aridx = arow * 8 + (colg ^ (arow & 7));
  int bbase[4];
#pragma unroll
  for (int f = 0; f < 4; ++f) {
    const int br = f * 16 + (lane & 15);
    bbase[f] = br * 128 + (colg ^ (br & 7));
  }

  // ---- epilogue constants ----
  const int dcol = lane & 15;
  const int drow = (lane >> 4) * 4;
  const int jj = j0 + dcol;
  const float bi  = biasc[jj];
  const float bfv = biasc[HDIM + jj];
  const float bg  = biasc[2 * HDIM + jj];
  const float bo  = biasc[3 * HDIM + jj];
  const float ci  = c2c[jj];
  const float cf  = c2c[HDIM + jj];
  const float co  = c2c[2 * HDIM + jj];
  const int eb0 = b0 + rf * 16 + drow;

  float c_reg[4];
#pragma unroll
  for (int r = 0; r < 4; ++r)
    c_reg[r] = c_st[(size_t)(eb0 + r) * HDIM + jj];

  __syncthreads();   // Bp ready

#pragma unroll 1
  for (int s = 0; s < W; ++s) {
    const __hip_bfloat16* hin = (s & 1) ? hb1 : hb0;
    __hip_bfloat16* hout      = (s & 1) ? hb0 : hb1;

    // issue ALL h loads for this step up front (latency pre-hidden)
    short8 hv[16];
    const __hip_bfloat16* hp = hin + hoff;
#pragma unroll
    for (int kc = 0; kc < 16; ++kc)
      hv[kc] = *(const short8*)(const void*)(hp + kc * 64);

    // issue xg loads early too (consumed in epilogue)
    const __hip_bfloat16* xr = xg + (size_t)s * BATCH * GDIM;
    float xgv[4][4];
    if (kh == 0) {
#pragma unroll
      for (int r = 0; r < 4; ++r)
#pragma unroll
        for (int f = 0; f < 4; ++f)
          xgv[r][f] = __bfloat162float(xr[(size_t)(eb0 + r) * GDIM + f * HDIM + jj]);
    }

    f32x4 acc[4];
#pragma unroll
    for (int f = 0; f < 4; ++f) acc[f] = (f32x4){0.f, 0.f, 0.f, 0.f};

    As[0][aslot] = hv[0];
    __syncthreads();
#pragma unroll
    for (int kc = 0; kc < 16; ++kc) {
      short8 af = As[kc & 1][aridx];
#pragma unroll
      for (int f = 0; f < 4; ++f)
        acc[f] = __builtin_amdgcn_mfma_f32_16x16x32_bf16(af, Bp[bbase[f] + kc * 8], acc[f], 0, 0, 0);
      if (kc < 15) As[(kc + 1) & 1][aslot] = hv[kc + 1];
      __syncthreads();
    }

    // k-half reduction through As (exactly 16 KB)
    float* red = (float*)&As[0][0];
    if (kh == 1) {
#pragma unroll
      for (int f = 0; f < 4; ++f)
#pragma unroll
        for (int r = 0; r < 4; ++r)
          red[(rf * 16 + drow + r) * 64 + f * 16 + dcol] = acc[f][r];
    }
    __syncthreads();
    if (kh == 0) {
#pragma unroll
      for (int r = 0; r < 4; ++r) {
        const int rr = (rf * 16 + drow + r) * 64 + dcol;
        float gI = acc[0][r] + red[rr +  0] + xgv[r][0] + bi;
        float gF = acc[1][r] + red[rr + 16] + xgv[r][1] + bfv;
        float gG = acc[2][r] + red[rr + 32] + xgv[r][2] + bg;
        float gO = acc[3][r] + red[rr + 48] + xgv[r][3] + bo;
        float cp = c_reg[r];
        float ig = sigmoidf_(gI + ci * cp);
        float fg = sigmoidf_(gF + cf * cp);
        float gg = tanh_(gG);
        float cn = fg * cp + ig * gg;
        float og = sigmoidf_(gO + co * cn);
        c_reg[r] = cn;
        hout[(size_t)(eb0 + r) * HDIM + jj] = __float2bfloat16(og * tanh_(cn));
      }
    }
    if (s < W - 1) grid_barrier(bar, xcd);
  }

  if (kh == 0) {
#pragma unroll
    for (int r = 0; r < 4; ++r)
      c_st[(size_t)(eb0 + r) * HDIM + jj] = c_reg[r];
  }
}

// ---------------------------------------------------------------------------
// Final FC: out[b][o] = h[b][:] . Wfc[o][:] + bfc[o]  (M=256,N=1024,K=1024)
// ---------------------------------------------------------------------------
__global__ __launch_bounds__(256, 1)
void fc_kernel(const __hip_bfloat16* __restrict__ h,
               const float* __restrict__ Wfc,
               const float* __restrict__ bfc,
               float* __restrict__ out)
{
  __shared__ short8 As8[512];
  __shared__ short8 Bs8[512];

  const int tid = threadIdx.x;
  const int wave = tid >> 6;
  const int lane = tid & 63;
  const int mtile = blockIdx.x >> 4;
  const int otile = blockIdx.x & 15;
  const int b0 = mtile * 64, o0 = otile * 64;

  const int r0 = tid >> 3;
  const int cg0 = tid & 7;

  f32x4 acc[4];
#pragma unroll
  for (int f = 0; f < 4; ++f) acc[f] = (f32x4){0.f, 0.f, 0.f, 0.f};

#pragma unroll 1
  for (int kc = 0; kc < 16; ++kc) {
    __syncthreads();
    As8[r0 * 8 + (cg0 ^ (r0 & 7))] =
        *(const short8*)(const void*)(h + (size_t)(b0 + r0) * HDIM + kc * 64 + cg0 * 8);
    As8[(r0 + 32) * 8 + (cg0 ^ (r0 & 7))] =
        *(const short8*)(const void*)(h + (size_t)(b0 + r0 + 32) * HDIM + kc * 64 + cg0 * 8);
    {
      const float* p0 = Wfc + (size_t)(o0 + r0) * HDIM + kc * 64 + cg0 * 8;
      const float* p1 = Wfc + (size_t)(o0 + r0 + 32) * HDIM + kc * 64 + cg0 * 8;
      f32x4 l0 = *(const f32x4*)p0, h0 = *(const f32x4*)(p0 + 4);
      f32x4 l1 = *(const f32x4*)p1, h1 = *(const f32x4*)(p1 + 4);
      short8 s0, s1;
#pragma unroll
      for (int e = 0; e < 4; ++e) {
        s0[e] = f2bf(l0[e]); s0[e + 4] = f2bf(h0[e]);
        s1[e] = f2bf(l1[e]); s1[e + 4] = f2bf(h1[e]);
      }
      Bs8[r0 * 8 + (cg0 ^ (r0 & 7))] = s0;
      Bs8[(r0 + 32) * 8 + (cg0 ^ (r0 & 7))] = s1;
    }
    __syncthreads();
#pragma unroll
    for (int s = 0; s < 2; ++s) {
      const int colg = s * 4 + (lane >> 4);
      const int ar = wave * 16 + (lane & 15);
      short8 af = As8[ar * 8 + (colg ^ (ar & 7))];
#pragma unroll
      for (int f = 0; f < 4; ++f) {
        const int br = f * 16 + (lane & 15);
        short8 bfq = Bs8[br * 8 + (colg ^ (br & 7))];
        acc[f] = __builtin_amdgcn_mfma_f32_16x16x32_bf16(af, bfq, acc[f], 0, 0, 0);
      }
    }
  }

  const int dcol = lane & 15;
  const int drow = (lane >> 4) * 4;
#pragma unroll
  for (int f = 0; f < 4; ++f) {
    const int o = o0 + f * 16 + dcol;
    const float bias = bfc[o];
#pragma unroll
    for (int r = 0; r < 4; ++r) {
      const int b = b0 + wave * 16 + drow + r;
      out[(size_t)b * 1024 + o] = acc[f][r] + bias;
    }
  }
}

// ---------------------------------------------------------------------------
extern "C" void kernel_launch(void* const* d_in, const int* in_sizes, int n_in,
                              void* d_out, int out_size, void* d_ws, size_t ws_size,
                              hipStream_t stream)
{
  const float* x   = (const float*)d_in[0];
  const float* Wx  = (const float*)d_in[1];
  const float* bx  = (const float*)d_in[2];
  const float* Wh  = (const float*)d_in[3];
  const float* bh  = (const float*)d_in[4];
  const float* c2c = (const float*)d_in[5];
  const float* Wfc = (const float*)d_in[6];
  const float* bfc = (const float*)d_in[7];
  float* out = (float*)d_out;

  char* ws = (char*)d_ws;
  // layout:
  //   [0,8M)    Whb   [8M,16M) Wxb   [16M,+16K) biasc
  //   [16M+64K) hb0 512K | hb1 512K   [17M+64K) c_st 1M
  //   [18M+64K) bar 4K                [19M,...) xg ring W*2MB
  __hip_bfloat16* Whb   = (__hip_bfloat16*)(ws);
  __hip_bfloat16* Wxb   = (__hip_bfloat16*)(ws + (8u << 20));
  float*          biasc = (float*)(ws + (16u << 20));
  __hip_bfloat16* hb0   = (__hip_bfloat16*)(ws + (16u << 20) + (1u << 16));
  __hip_bfloat16* hb1   = (__hip_bfloat16*)(ws + (16u << 20) + (1u << 16) + (1u << 19));
  float*          c_st  = (float*)(ws + (17u << 20) + (1u << 16));
  unsigned*       bar   = (unsigned*)(ws + (18u << 20) + (1u << 16));
  __hip_bfloat16* xgbuf = (__hip_bfloat16*)(ws + (19u << 20));

  const size_t xg_off = (size_t)19 << 20;
  int W = 2;
  for (int cand = 512; cand >= 2; cand >>= 1) {
    size_t need = xg_off + (size_t)cand * BATCH * GDIM * sizeof(__hip_bfloat16);
    if (need <= ws_size) { W = cand; break; }
  }

  hipMemsetAsync(hb0, 0, (size_t)BATCH * HDIM * sizeof(__hip_bfloat16), stream);
  hipMemsetAsync(c_st, 0, (size_t)BATCH * HDIM * sizeof(float), stream);
  hipMemsetAsync(bar, 0, 4096, stream);

  pack_kernel<<<1024, 256, 0, stream>>>(Wh, Wx, bx, bh, Whb, Wxb, biasc);

  const int NW = T_STEPS / W;
  for (int w = 0; w < NW; ++w) {
    xg_gemm<<<W * 64, 512, 0, stream>>>(x, Wxb, xgbuf, w * W);
    lstm_persist<<<256, 512, 0, stream>>>(xgbuf, Whb, biasc, c2c, hb0, hb1, c_st, bar, W);
  }

  fc_kernel<<<64, 256, 0, stream>>>(hb0, Wfc, bfc, out);
}